// Round 9
// baseline (16.871 us; speedup 1.0000x reference)
//
#include <hip/hip_runtime.h>
#include <hip/hip_bf16.h>

// B=16, N=100, D=256, C=2, E=N*(N-1)=9900.
// Complete-graph GCN collapses to a per-batch MLP:
//   gcn_conv(x) = mean_n(x) @ W + b  (deg==100, norm==1/100, incl. self-loop)
// R8: attack the measured ~80 GB/s/CU weight-stream ceiling as an MLP
// (memory-level-parallelism) limit, not a port limit:
//   - layers 1/2: explicit 16-deep register load-batches (16 x f32x4 in
//     flight per thread -> 64KB/CU in flight, covers ~90ns L2 latency)
//   - chunk-phase rotation per block decorrelates same-line L2 access
//     across the 256 lockstep blocks
//   - grid 256 = (16 b x 16 g): every CU busy; layer3 slice 16 cols
//     (32KB Wl1 per block); bbox/out writes spread 2x wider
// Calibration: node OH ~3.2us, barrier ~5-8us (never), per-CU stream
// ~80 GB/s @ depth 8 (under test -> expect ~135 at depth 16).

#define BB 16
#define NN 100
#define DD 256
#define EE 9900
#define GG 16
#define CHUNK 619           // ceil(EE/GG)

typedef float f32x4 __attribute__((ext_vector_type(4)));
typedef float f32x2 __attribute__((ext_vector_type(2)));

__device__ __forceinline__ f32x4 ldg_nt4(const float* p) {
    return __builtin_nontemporal_load(reinterpret_cast<const f32x4*>(p));
}
__device__ __forceinline__ f32x4 ld4(const float* p) {
    return *reinterpret_cast<const f32x4*>(p);
}
__device__ __forceinline__ void stg_nt4(float* p, f32x4 v) {
    __builtin_nontemporal_store(v, reinterpret_cast<f32x4*>(p));
}

__global__ __launch_bounds__(256) void k_mlp(
    const float* __restrict__ x,        // [B,N,D]
    const float* __restrict__ bboxes,   // [B,N,4]
    const int*   __restrict__ edge,     // [2,E]
    const float* __restrict__ W1, const float* __restrict__ b1,
    const float* __restrict__ W2, const float* __restrict__ b2,
    const float* __restrict__ Wl1, const float* __restrict__ bl1,
    const float* __restrict__ Wf,
    float* __restrict__ ws,             // [16][16][2] partial logits
    float* __restrict__ out)
{
    const int b  = blockIdx.x >> 4;
    const int g  = blockIdx.x & 15;
    const int t  = threadIdx.x;
    const int c4 = t & 63;          // column quad 0..63
    const int kq = t >> 6;          // 0..3
    const int ph = blockIdx.x & 3;  // chunk-phase rotation

    __shared__ __align__(16) float sX[DD];
    __shared__ __align__(16) float sY[DD];
    __shared__ __align__(16) f32x4 sPf[256];
    __shared__ float sR[32 * 4];    // layer3 stage-1 partials (f32x4 as 4 floats)
    __shared__ float sL0[4], sL1[4];

    // ---- xbar partials: 4 row-groups of 25, 13+12 deep load batches ----
    {
        const float* xp = x + ((size_t)b * NN + kq * 25) * DD + c4 * 4;
        f32x4 a = {0.f, 0.f, 0.f, 0.f};
        {
            f32x4 v[13];
            #pragma unroll
            for (int i = 0; i < 13; ++i) v[i] = ld4(xp + (size_t)i * DD);
            #pragma unroll
            for (int i = 0; i < 13; ++i) a += v[i];
        }
        {
            f32x4 v[12];
            #pragma unroll
            for (int i = 0; i < 12; ++i) v[i] = ld4(xp + (size_t)(13 + i) * DD);
            #pragma unroll
            for (int i = 0; i < 12; ++i) a += v[i];
        }
        sPf[kq * 64 + c4] = a;
    }

    // ---- bbox-pair writes for this block's edge chunk (overlaps streams) ----
    {
        const int e0 = g * CHUNK;
        const int e1 = min(e0 + CHUNK, EE);
        float* boutf = out + (size_t)BB * EE * 2;
        for (int e = e0 + t; e < e1; e += 256) {
            const int s  = edge[e];
            const int d2 = edge[EE + e];
            const size_t idx = (size_t)b * EE + e;
            f32x4 bs = ld4(bboxes + (size_t)(b * NN + s) * 4);
            f32x4 bd = ld4(bboxes + (size_t)(b * NN + d2) * 4);
            stg_nt4(boutf + idx * 8, bs);
            stg_nt4(boutf + idx * 8 + 4, bd);
        }
    }
    __syncthreads();
    if (t < 64) {
        f32x4 s = sPf[t] + sPf[64 + t] + sPf[128 + t] + sPf[192 + t];
        ((f32x4*)sX)[t] = s * 0.01f;
    }
    __syncthreads();

    // ---- layer 1: sY = relu(sX @ W1 + b1), 16-deep load batches ----
    {
        const float* Wp = W1 + (size_t)(kq * 64) * DD + c4 * 4;
        const float* xk = sX + kq * 64;
        f32x4 acc = {0.f, 0.f, 0.f, 0.f};
        #pragma unroll
        for (int cc = 0; cc < 4; ++cc) {
            const int kb = ((ph + cc) & 3) * 16;
            f32x4 w[16];
            #pragma unroll
            for (int i = 0; i < 16; ++i)
                w[i] = ldg_nt4(Wp + (size_t)(kb + i) * DD);
            #pragma unroll
            for (int i = 0; i < 16; ++i)
                acc += xk[kb + i] * w[i];
        }
        __syncthreads();
        sPf[kq * 64 + c4] = acc;
        __syncthreads();
        if (t < 64) {
            f32x4 s = sPf[t] + sPf[64 + t] + sPf[128 + t] + sPf[192 + t]
                    + ld4(b1 + t * 4);
            f32x4 z = {0.f, 0.f, 0.f, 0.f};
            ((f32x4*)sY)[t] = __builtin_elementwise_max(s, z);
        }
        __syncthreads();
    }

    // ---- layer 2: sX = relu(sY @ W2 + b2), 16-deep load batches ----
    {
        const float* Wp = W2 + (size_t)(kq * 64) * DD + c4 * 4;
        const float* xk = sY + kq * 64;
        f32x4 acc = {0.f, 0.f, 0.f, 0.f};
        #pragma unroll
        for (int cc = 0; cc < 4; ++cc) {
            const int kb = ((ph + cc) & 3) * 16;
            f32x4 w[16];
            #pragma unroll
            for (int i = 0; i < 16; ++i)
                w[i] = ldg_nt4(Wp + (size_t)(kb + i) * DD);
            #pragma unroll
            for (int i = 0; i < 16; ++i)
                acc += xk[kb + i] * w[i];
        }
        __syncthreads();
        sPf[kq * 64 + c4] = acc;
        __syncthreads();
        if (t < 64) {
            f32x4 s = sPf[t] + sPf[64 + t] + sPf[128 + t] + sPf[192 + t]
                    + ld4(b2 + t * 4);
            f32x4 z = {0.f, 0.f, 0.f, 0.f};
            ((f32x4*)sX)[t] = __builtin_elementwise_max(s, z);
        }
        __syncthreads();
    }

    // ---- layer 3 (cols [16g,16g+16)): h = relu(z2 @ (Wl1_t+Wl1_b) + bl1),
    //      partial logits for this slice. 8-deep load batch per thread. ----
    {
        const int c  = t & 3;       // col-quad within slice (4 quads = 16 cols)
        const int kg = t >> 2;      // 0..63, k-chunk of 4
        const float* Wp0 = Wl1 + (size_t)(kg * 4) * DD + g * 16 + c * 4;
        const float* Wp1 = Wp0 + (size_t)DD * DD;
        const float* xk = sX + kg * 4;
        f32x4 w0[4], w1[4];
        #pragma unroll
        for (int i = 0; i < 4; ++i) w0[i] = ldg_nt4(Wp0 + (size_t)i * DD);
        #pragma unroll
        for (int i = 0; i < 4; ++i) w1[i] = ldg_nt4(Wp1 + (size_t)i * DD);
        f32x4 acc = {0.f, 0.f, 0.f, 0.f};
        #pragma unroll
        for (int i = 0; i < 4; ++i)
            acc += xk[i] * (w0[i] + w1[i]);
        __syncthreads();
        sPf[kg * 4 + c] = acc;
        __syncthreads();
        // stage 1: 32 threads, each sums 8 of 64 k-groups for its col-quad
        if (t < 32) {
            const int c2 = t & 3, r = t >> 2;       // r 0..7
            f32x4 s = {0.f, 0.f, 0.f, 0.f};
            #pragma unroll
            for (int j = 0; j < 8; ++j)
                s += sPf[(r * 8 + j) * 4 + c2];
            *(f32x4*)&sR[t * 4] = s;
        }
        __syncthreads();
        // stage 2: 4 threads finalize col-quads, partial logits
        if (t < 4) {
            f32x4 s = {0.f, 0.f, 0.f, 0.f};
            #pragma unroll
            for (int r = 0; r < 8; ++r)
                s += *(const f32x4*)&sR[(r * 4 + t) * 4];
            const int c0 = g * 16 + t * 4;
            s += ld4(bl1 + c0);
            f32x4 z = {0.f, 0.f, 0.f, 0.f};
            f32x4 h = __builtin_elementwise_max(s, z);
            sL0[t] = h.x * Wf[(c0 + 0) * 2] + h.y * Wf[(c0 + 1) * 2]
                   + h.z * Wf[(c0 + 2) * 2] + h.w * Wf[(c0 + 3) * 2];
            sL1[t] = h.x * Wf[(c0 + 0) * 2 + 1] + h.y * Wf[(c0 + 1) * 2 + 1]
                   + h.z * Wf[(c0 + 2) * 2 + 1] + h.w * Wf[(c0 + 3) * 2 + 1];
        }
        __syncthreads();
        if (t == 0) {
            float l0 = sL0[0] + sL0[1] + sL0[2] + sL0[3];
            float l1 = sL1[0] + sL1[1] + sL1[2] + sL1[3];
            ws[(b * GG + g) * 2 + 0] = l0;
            ws[(b * GG + g) * 2 + 1] = l1;
        }
    }
}

// ---- Node B: assemble logits + log_softmax, write probs only ----
__global__ __launch_bounds__(256) void k_probs(
    const float* __restrict__ ws,       // [16][16][2]
    const float* __restrict__ bf,
    float* __restrict__ out)
{
    const int b = blockIdx.y;
    const int e = blockIdx.x * 256 + threadIdx.x;

    __shared__ float sp0, sp1;
    if (threadIdx.x == 0) {
        float L0 = bf[0], L1 = bf[1];
        #pragma unroll
        for (int q = 0; q < GG; ++q) {
            L0 += ws[(b * GG + q) * 2 + 0];
            L1 += ws[(b * GG + q) * 2 + 1];
        }
        float m  = fmaxf(L0, L1);
        float ls = logf(expf(L0 - m) + expf(L1 - m));
        sp0 = L0 - m - ls;
        sp1 = L1 - m - ls;
    }
    __syncthreads();

    if (e < EE) {
        f32x2 p = {sp0, sp1};
        __builtin_nontemporal_store(
            p, reinterpret_cast<f32x2*>(out) + (size_t)b * EE + e);
    }
}

extern "C" void kernel_launch(void* const* d_in, const int* in_sizes, int n_in,
                              void* d_out, int out_size, void* d_ws, size_t ws_size,
                              hipStream_t stream) {
    const float* hidden  = (const float*)d_in[0];
    const float* bboxes  = (const float*)d_in[1];
    const float* W1      = (const float*)d_in[2];
    const float* b1      = (const float*)d_in[3];
    const float* W2      = (const float*)d_in[4];
    const float* b2      = (const float*)d_in[5];
    const float* Wl1     = (const float*)d_in[6];
    const float* bl1     = (const float*)d_in[7];
    const float* Wf      = (const float*)d_in[8];
    const float* bf      = (const float*)d_in[9];
    const int*   edge    = (const int*)d_in[10];

    float* ws  = (float*)d_ws;      // 512 floats: partial logits
    float* out = (float*)d_out;

    k_mlp<<<BB * GG, 256, 0, stream>>>(hidden, bboxes, edge,
                                       W1, b1, W2, b2, Wl1, bl1, Wf,
                                       ws, out);

    dim3 og((EE + 255) / 256, BB);
    k_probs<<<og, 256, 0, stream>>>(ws, bf, out);
}